// Round 15
// baseline (236.068 us; speedup 1.0000x reference)
//
#include <hip/hip_runtime.h>
#include <hip/hip_bf16.h>
#include <math.h>

#define T_AUDIO 441000
#define NH   2048
#define HOP  1024
#define NBINS 2049
#define NFRAMES 431
#define PAD  2048

// GEMM padded dims (bf16 buffers, zero-filled padding -> no guards in GEMM)
#define GP  2176   // padded g (M) = 17*128
#define KP  2112   // padded f (K) = 66*32
#define TPN 448    // padded frames per nc (7*64)
#define NKT2 66    // K-steps of 32

#define NBLK 108   // istft blocks per njc (4 frames each)
#define SPAN 7168  // 4096 + 3*1024 samples per istft block

#define NSTFT (4 * NFRAMES)                      // 1724
#define NCONV ((4 * GP * KP / 8 + 255) / 256)    // 8976
#define NPREP (NSTFT + NCONV + 4)                // +4 Xb pad-row blocks

#define TWO_PI 6.2831853071795864769f

// LDS index padding for FFT buffers: +1 float2 per 16
#define PADI(i) ((i) + ((i) >> 4))

typedef __bf16 bf16_t;
typedef bf16_t bf16x8 __attribute__((ext_vector_type(8)));
typedef bf16_t bf16x4 __attribute__((ext_vector_type(4)));
typedef float f32x4 __attribute__((ext_vector_type(4)));
typedef float f32x4u __attribute__((ext_vector_type(4), aligned(4)));
typedef _Float16 h16;
typedef h16 h16x2 __attribute__((ext_vector_type(2)));

__device__ __forceinline__ unsigned pack_bf2(float a, float b) {
    union { bf16_t h; unsigned short u; } ca, cb;
    ca.h = (bf16_t)a; cb.h = (bf16_t)b;
    return (unsigned)ca.u | ((unsigned)cb.u << 16);
}
__device__ __forceinline__ float2 unpack_bf2(unsigned v) {
    union { unsigned u; float f; } a, b;
    a.u = v << 16;
    b.u = v & 0xffff0000u;
    return make_float2(a.f, b.f);
}

__device__ __forceinline__ float2 cadd(float2 a, float2 b) { return make_float2(a.x + b.x, a.y + b.y); }
__device__ __forceinline__ float2 csub(float2 a, float2 b) { return make_float2(a.x - b.x, a.y - b.y); }
__device__ __forceinline__ float2 cmul(float2 a, float2 b) {       // a*b
    return make_float2(a.x * b.x - a.y * b.y, a.x * b.y + a.y * b.x);
}
__device__ __forceinline__ float2 cmulc(float2 u, float2 w) {      // u*conj(w)
    return make_float2(u.x * w.x + u.y * w.y, u.y * w.x - u.x * w.y);
}

// twiddle table: tw[k] = (cos(2*pi*k/4096), sin(2*pi*k/4096))
__global__ void k_tab(float2* __restrict__ tw) {
    int i = blockIdx.x * 256 + threadIdx.x;
    if (i < 4096) {
        float s, c;
        sincosf((float)i * (TWO_PI / 4096.0f), &s, &c);
        tw[i] = make_float2(c, s);
    }
}

// ---- register-fed Stockham FFT pieces (len 2048, 256 threads) ----

__device__ __forceinline__ void load_own(float2 v[8], const float2* x, int tid) {
    #pragma unroll
    for (int k = 0; k < 8; k++) v[k] = x[PADI(tid + 256 * k)];
}

template<bool FWD>
__device__ __forceinline__ void r8_sweep_store(const float2 v[8], float2* x,
        int tid, int s, int ls, int fac, const float2* __restrict__ tw) {
    const float sgn = FWD ? -1.0f : 1.0f;
    const float R2 = 0.70710678118654752440f;
    int q = tid & (s - 1);
    int p = tid >> ls;
    int e = p * fac;
    float2 w[7];
    #pragma unroll
    for (int k = 0; k < 7; k++) w[k] = tw[e * (k + 1)];
    float2 s0 = cadd(v[0], v[4]), s1 = cadd(v[1], v[5]),
           s2 = cadd(v[2], v[6]), s3 = cadd(v[3], v[7]);
    float2 d0 = csub(v[0], v[4]), d1 = csub(v[1], v[5]),
           d2 = csub(v[2], v[6]), d3 = csub(v[3], v[7]);
    float2 X0, X1, X2, X3, X4, X5, X6, X7;
    {
        float2 t0 = cadd(s0, s2), t1 = csub(s0, s2);
        float2 t2 = cadd(s1, s3), t3 = csub(s1, s3);
        float2 it3 = make_float2(-sgn * t3.y, sgn * t3.x);
        X0 = cadd(t0, t2); X4 = csub(t0, t2);
        X2 = cadd(t1, it3); X6 = csub(t1, it3);
    }
    {
        float2 e0 = d0;
        float2 e1 = make_float2(R2 * (d1.x - sgn * d1.y), R2 * (sgn * d1.x + d1.y));
        float2 e2 = make_float2(-sgn * d2.y, sgn * d2.x);
        float2 e3 = make_float2(-R2 * (d3.x + sgn * d3.y), R2 * (sgn * d3.x - d3.y));
        float2 t0 = cadd(e0, e2), t1 = csub(e0, e2);
        float2 t2 = cadd(e1, e3), t3 = csub(e1, e3);
        float2 it3 = make_float2(-sgn * t3.y, sgn * t3.x);
        X1 = cadd(t0, t2); X5 = csub(t0, t2);
        X3 = cadd(t1, it3); X7 = csub(t1, it3);
    }
    int ob = q + 8 * s * p;
    x[PADI(ob)] = X0;
    float2 XX[7] = {X1, X2, X3, X4, X5, X6, X7};
    #pragma unroll
    for (int k = 0; k < 7; k++) {
        float2 u = XX[k];
        x[PADI(ob + s * (k + 1))] = FWD ? cmulc(u, w[k]) : cmul(w[k], u);
    }
}

__device__ __forceinline__ void r4_final_reg(const float2 v[8], float2 o[8],
                                             float sgn) {
    #pragma unroll
    for (int h = 0; h < 2; h++) {
        float2 c0 = v[h], c1 = v[h + 2], c2 = v[h + 4], c3 = v[h + 6];
        float2 t0 = cadd(c0, c2), t1 = csub(c0, c2);
        float2 t2 = cadd(c1, c3), t3 = csub(c1, c3);
        float2 it3 = make_float2(-sgn * t3.y, sgn * t3.x);
        o[h]     = cadd(t0, t2);
        o[h + 2] = cadd(t1, it3);
        o[h + 4] = csub(t0, t2);
        o[h + 6] = csub(t1, it3);
    }
}

template<bool FWD>
__device__ __forceinline__ void fft_mid(float2 v[8], float2* buf, int tid,
                                        const float2* __restrict__ tw) {
    r8_sweep_store<FWD>(v, buf, tid, 1, 0, 2, tw);
    __syncthreads();
    load_own(v, buf, tid);
    __syncthreads();
    r8_sweep_store<FWD>(v, buf, tid, 8, 3, 16, tw);
    __syncthreads();
    load_own(v, buf, tid);
    __syncthreads();
    r8_sweep_store<FWD>(v, buf, tid, 64, 6, 128, tw);
    __syncthreads();
    load_own(v, buf, tid);
    __syncthreads();
}

// Fused prep: [0,NSTFT) STFT; [NSTFT,NSTFT+NCONV) convW; last 4 = Xb pad rows.
__global__ __launch_bounds__(256) void k_prep(const float* __restrict__ audio,
        const float* __restrict__ W, bf16_t* __restrict__ Wb,
        bf16_t* __restrict__ Xb, unsigned* __restrict__ ph,
        const float2* __restrict__ tw) {
    __shared__ float2 buf[2176];
    int bid = blockIdx.x;
    int tid = threadIdx.x;
    if (bid >= NSTFT) {
        if (bid >= NSTFT + NCONV) {
            // ---- Xb pad rows 431..447 for one nc ----
            int nc = bid - NSTFT - NCONV;
            bf16_t* dst = Xb + ((size_t)nc * TPN + NFRAMES) * KP;
            bf16x8 z = {};
            for (int i = tid; i < (TPN - NFRAMES) * KP / 8; i += 256)
                *(bf16x8*)(dst + (size_t)i * 8) = z;
            return;
        }
        // ---- convW path (vectorized dwordx4 loads) ----
        size_t idx = (size_t)(bid - NSTFT) * 256 + tid;
        size_t total = (size_t)4 * GP * KP / 8;
        if (idx >= total) return;
        size_t e = idx * 8;
        int f0 = (int)(e % KP);
        size_t rem = e / KP;
        int g = (int)(rem % GP);
        int j = (int)(rem / GP);
        bf16x8 v = {};
        if (g < NBINS) {
            const float* src = W + ((size_t)j * NBINS + g) * NBINS;
            if (f0 + 7 < NBINS) {
                f32x4u a0 = *(const f32x4u*)(src + f0);
                f32x4u a1 = *(const f32x4u*)(src + f0 + 4);
                #pragma unroll
                for (int r = 0; r < 4; r++) { v[r] = (bf16_t)a0[r]; v[r + 4] = (bf16_t)a1[r]; }
            } else {
                #pragma unroll
                for (int r = 0; r < 8; r++) {
                    int f = f0 + r;
                    v[r] = (bf16_t)(f < NBINS ? src[f] : 0.0f);
                }
            }
        }
        *(bf16x8*)(Wb + e) = v;
        return;
    }
    // ---- stft path ----
    int nc = bid / NFRAMES;
    int fr = bid - nc * NFRAMES;
    const float* a = audio + (size_t)nc * T_AUDIO;
    int base = fr * HOP - PAD;
    float2 v[8];
    #pragma unroll
    for (int it = 0; it < 8; it++) {
        int m = tid + it * 256;
        float4 tt = ((const float4*)tw)[m];
        float w0 = 0.5f - 0.5f * tt.x, w1 = 0.5f - 0.5f * tt.z;
        int x0 = base + 2 * m;
        if (x0 >= 0 && x0 + 1 < T_AUDIO) {          // fast path: float2 load
            float2 av = *(const float2*)(a + x0);
            v[it] = make_float2(av.x * w0, av.y * w1);
        } else {
            int r0 = x0, r1 = x0 + 1;
            r0 = r0 < 0 ? -r0 : (r0 >= T_AUDIO ? 2 * T_AUDIO - 2 - r0 : r0);
            r1 = r1 < 0 ? -r1 : (r1 >= T_AUDIO ? 2 * T_AUDIO - 2 - r1 : r1);
            v[it] = make_float2(a[r0] * w0, a[r1] * w1);
        }
    }
    fft_mid<true>(v, buf, tid, tw);
    {
        float2 o[8];
        r4_final_reg(v, o, -1.0f);
        #pragma unroll
        for (int it = 0; it < 8; it++) buf[PADI(tid + 256 * it)] = o[it];
    }
    __syncthreads();
    size_t orow = ((size_t)nc * NFRAMES + fr) * KP;
    bf16_t* Xrow = Xb + ((size_t)nc * TPN + fr) * KP;
    for (int k = tid; k < NBINS; k += 256) {
        float2 Zk = buf[PADI(k & 2047)];
        float2 Zm = buf[PADI((2048 - k) & 2047)];
        float ex = 0.5f * (Zk.x + Zm.x), ey = 0.5f * (Zk.y - Zm.y);
        float ox = 0.5f * (Zk.y + Zm.y), oy = -0.5f * (Zk.x - Zm.x);
        float2 w = tw[k];
        float re = ex + w.x * ox + w.y * oy;
        float im = ey + w.x * oy - w.y * ox;
        float mag = sqrtf(re * re + im * im);
        float inv = 1.0f / (mag + 1e-10f);
        Xrow[k] = (bf16_t)mag;
        ph[orow + k] = pack_bf2(re * inv, im * inv);
    }
    // zero the k-tail of this row (replaces global memset of Xb)
    for (int k = NBINS + tid; k < KP; k += 256) Xrow[k] = (bf16_t)0.0f;
}

// V[jnc][t][g] = relu(sum_f W[j][g][f]*X[nc][t][f] + b[j][g]), bf16 out.
// r7 geometry (BM=128, BN=64), now BK=32 ping-pong with COUNTED vmcnt(3) +
// raw s_barrier (T4): next tile's 3 global_load_lds stay in flight across
// the barrier and land under the current tile's MFMA phase. LDS total 24KB
// (2 x 12KB) -> same residency as the proven single-buffer. Swizzle for
// 64B rows: chunk c ^= (r>>2)&3 -> 2-way bank aliasing (free).
// XCD-grouped 1D grid (72 groups x 28 = 2016, 1904 real).
__global__ __launch_bounds__(256) void k_gemm_mfma(const bf16_t* __restrict__ Wb,
        const float* __restrict__ bias, const bf16_t* __restrict__ Xb,
        bf16_t* __restrict__ V) {
    __shared__ bf16_t As[2][128 * 32];   // 2 x 8 KB
    __shared__ bf16_t Bs[2][64 * 32];    // 2 x 4 KB
    int id = blockIdx.x;
    int xcd = id & 7, nn = id >> 3;
    int G = xcd + 8 * (nn / 28);      // group = (j,g0); G%8 == xcd
    if (G >= 68) return;              // 72-group padding (block-uniform exit)
    int m28 = nn % 28;
    int j  = G / 17;
    int g0 = (G % 17) * 128;
    int nc = m28 / 7;
    int t0 = (m28 % 7) * 64;
    const bf16_t* A = Wb + ((size_t)j * GP + g0) * KP;
    const bf16_t* B = Xb + ((size_t)nc * TPN + t0) * KP;
    int tid = threadIdx.x;
    int lane = tid & 63, wid = tid >> 6;
    int wm = wid >> 1, wn = wid & 1;

    // staging: slot s = 16B chunk; r = s>>2 (row), c = s&3;
    // global chunk cg = c ^ ((r>>2)&3)  (involution; LDS stays linear)
    const bf16_t* srcA[2];
    #pragma unroll
    for (int i = 0; i < 2; i++) {
        int s = i * 256 + tid;
        int r = s >> 2, cc = (s & 3) ^ ((r >> 2) & 3);
        srcA[i] = A + (size_t)r * KP + cc * 8;
    }
    const bf16_t* srcB0;
    {
        int s = tid;
        int r = s >> 2, cc = (s & 3) ^ ((r >> 2) & 3);
        srcB0 = B + (size_t)r * KP + cc * 8;
    }

#define STAGE(bufsel, koff)                                                    \
    {                                                                          \
        _Pragma("unroll")                                                      \
        for (int i = 0; i < 2; i++)                                            \
            __builtin_amdgcn_global_load_lds(                                  \
                (const __attribute__((address_space(1))) void*)(srcA[i] + (koff)), \
                (__attribute__((address_space(3))) void*)(&As[bufsel][(i * 256 + tid) * 8]), \
                16, 0, 0);                                                     \
        __builtin_amdgcn_global_load_lds(                                      \
            (const __attribute__((address_space(1))) void*)(srcB0 + (koff)),   \
            (__attribute__((address_space(3))) void*)(&Bs[bufsel][tid * 8]),   \
            16, 0, 0);                                                         \
    }

    int laneLo = lane & 15, laneHi = lane >> 4;
    int offA[4], offB[2];
    #pragma unroll
    for (int mm = 0; mm < 4; mm++) {
        int r = wm * 64 + mm * 16 + laneLo;
        offA[mm] = r * 64 + ((laneHi ^ ((r >> 2) & 3)) << 4);
    }
    #pragma unroll
    for (int n = 0; n < 2; n++) {
        int r = wn * 32 + n * 16 + laneLo;
        offB[n] = r * 64 + ((laneHi ^ ((r >> 2) & 3)) << 4);
    }

    f32x4 acc[4][2];
    #pragma unroll
    for (int mm = 0; mm < 4; mm++)
        #pragma unroll
        for (int n = 0; n < 2; n++)
            acc[mm][n] = (f32x4){0.f, 0.f, 0.f, 0.f};

    STAGE(0, 0);
    STAGE(1, 32);
    for (int t = 0; t < NKT2; ++t) {
        // counted wait: current tile's 3 loads done; next tile's 3 keep flying
        if (t == NKT2 - 1) asm volatile("s_waitcnt vmcnt(0)" ::: "memory");
        else               asm volatile("s_waitcnt vmcnt(3)" ::: "memory");
        __builtin_amdgcn_s_barrier();

        const char* aB = (const char*)&As[t & 1][0];
        const char* bB = (const char*)&Bs[t & 1][0];
        bf16x8 af[4], bfr[2];
        #pragma unroll
        for (int mm = 0; mm < 4; mm++)
            af[mm] = *(const bf16x8*)(aB + offA[mm]);
        #pragma unroll
        for (int n = 0; n < 2; n++)
            bfr[n] = *(const bf16x8*)(bB + offB[n]);
        #pragma unroll
        for (int mm = 0; mm < 4; mm++)
            #pragma unroll
            for (int n = 0; n < 2; n++)
                acc[mm][n] = __builtin_amdgcn_mfma_f32_16x16x32_bf16(
                    af[mm], bfr[n], acc[mm][n], 0, 0, 0);

        __builtin_amdgcn_s_barrier();   // all waves done reading buf[t&1]
        if (t + 2 < NKT2) STAGE(t & 1, (t + 2) * 32);
    }
#undef STAGE

    int jnc = j * 4 + nc;
    int colT = laneLo;
    int rowB = laneHi * 4;
    #pragma unroll
    for (int n = 0; n < 2; n++) {
        int t = t0 + wn * 32 + n * 16 + colT;
        if (t >= NFRAMES) continue;
        size_t vrow = ((size_t)jnc * NFRAMES + t) * KP;
        #pragma unroll
        for (int mm = 0; mm < 4; mm++) {
            int g = g0 + wm * 64 + mm * 16 + rowB;
            if (g + 3 < NBINS) {
                bf16x4 o;
                #pragma unroll
                for (int r = 0; r < 4; r++)
                    o[r] = (bf16_t)fmaxf(acc[mm][n][r] + bias[j * NBINS + g + r], 0.0f);
                *(bf16x4*)(V + vrow + g) = o;
            } else {
                #pragma unroll
                for (int r = 0; r < 4; r++) {
                    int gg = g + r;
                    if (gg < NBINS)
                        V[vrow + gg] = (bf16_t)fmaxf(acc[mm][n][r] + bias[j * NBINS + gg], 0.0f);
                }
            }
        }
    }
}

// One block per (jnc, 4 frames). Per frame: stage V row (4KB) + ph row (8KB)
// into LDS via coalesced global_load_lds (issued one frame AHEAD, latency
// hides under the FFT); z-build reads LDS; final radix-4 + window + OLA in
// registers. XCD/j-grouped 1D grid (1728 = 8 x 216).
__global__ __launch_bounds__(256) void k_istft(const bf16_t* __restrict__ V,
        const unsigned* __restrict__ ph, const float2* __restrict__ tw,
        h16* __restrict__ strips) {
    __shared__ float2 buf[2176];
    __shared__ __align__(16) unsigned char stg[12336];
    bf16_t*   Vs = (bf16_t*)stg;              // 2056 bf16 (4112 B)
    unsigned* Ps = (unsigned*)(stg + 4112);   // 2052 u32  (8208 B)
    int id = blockIdx.x;                 // 1728 = 8 XCD x 216
    int xcd = id & 7, slot = id >> 3;
    int wgid = xcd * 216 + slot;         // bijective
    int j = wgid & 3;
    int t4 = wgid >> 2;                  // nc*108 + b
    int nc = t4 / NBLK;
    int b  = t4 - nc * NBLK;
    int njc = (nc >> 1) * 8 + j * 2 + (nc & 1);
    int jnc = j * 4 + nc;
    int tid = threadIdx.x;
    const float scale = 1.0f / 2048.0f;
    float2 acc[14];
    #pragma unroll
    for (int u = 0; u < 14; u++) acc[u] = make_float2(0.f, 0.f);

#define STAGE_F(fr_)                                                           \
    {                                                                          \
        const bf16_t* vsrc = V + ((size_t)jnc * NFRAMES + (fr_)) * KP;         \
        const unsigned* psrc = ph + ((size_t)nc * NFRAMES + (fr_)) * KP;       \
        __builtin_amdgcn_global_load_lds(                                      \
            (const __attribute__((address_space(1))) void*)(vsrc + tid * 8),   \
            (__attribute__((address_space(3))) void*)(Vs + tid * 8), 16, 0, 0);\
        __builtin_amdgcn_global_load_lds(                                      \
            (const __attribute__((address_space(1))) void*)(psrc + tid * 4),   \
            (__attribute__((address_space(3))) void*)(Ps + tid * 4), 16, 0, 0);\
        __builtin_amdgcn_global_load_lds(                                      \
            (const __attribute__((address_space(1))) void*)(psrc + 1024 + tid * 4), \
            (__attribute__((address_space(3))) void*)(Ps + 1024 + tid * 4), 16, 0, 0); \
        if (tid == 0) {                                                        \
            __builtin_amdgcn_global_load_lds(                                  \
                (const __attribute__((address_space(1))) void*)(vsrc + 2048),  \
                (__attribute__((address_space(3))) void*)(Vs + 2048), 16, 0, 0); \
            __builtin_amdgcn_global_load_lds(                                  \
                (const __attribute__((address_space(1))) void*)(psrc + 2048),  \
                (__attribute__((address_space(3))) void*)(Ps + 2048), 16, 0, 0); \
        }                                                                      \
    }

    STAGE_F(b * 4);
    __syncthreads();   // vmcnt(0) drain + barrier: stage ready

    #pragma unroll
    for (int p = 0; p < 4; p++) {
        int fr = b * 4 + p;
        if (fr < NFRAMES) {   // block-uniform guard
            float2 v[8];
            // z-build from staged LDS (2-way/conflict-free reads)
            #pragma unroll
            for (int it = 0; it < 8; it++) {
                int k = tid + it * 256;
                int km = 2048 - k;
                float vk = (float)Vs[k];
                float2 pk = unpack_bf2(Ps[k]);
                float vm = (float)Vs[km];
                float2 pm = unpack_bf2(Ps[km]);
                float2 Yk = make_float2(vk * pk.x, vk * pk.y);
                float2 Ym = make_float2(vm * pm.x, vm * pm.y);
                float ex = 0.5f * (Yk.x + Ym.x), ey = 0.5f * (Yk.y - Ym.y);
                float wx = 0.5f * (Yk.x - Ym.x), wy = 0.5f * (Yk.y + Ym.y);
                float2 w = tw[k];
                float ox_ = w.x * wx - w.y * wy;
                float oy_ = w.x * wy + w.y * wx;
                v[it] = make_float2(ex - oy_, ey + ox_);
            }
            __syncthreads();            // all waves done reading the stage
            if (p < 3) STAGE_F(fr + 1); // prefetch next frame (lands by the
                                        // fft's first barrier; overlaps sweep0)
            fft_mid<false>(v, buf, tid, tw);
            float2 o[8];
            r4_final_reg(v, o, 1.0f);
            #pragma unroll
            for (int it = 0; it < 8; it++) {
                int m = tid + it * 256;
                float4 tt = ((const float4*)tw)[m];
                acc[2 * p + it].x += o[it].x * scale * (0.5f - 0.5f * tt.x);
                acc[2 * p + it].y += o[it].y * scale * (0.5f - 0.5f * tt.z);
            }
        }
    }
#undef STAGE_F
    h16* dst = strips + ((size_t)njc * NBLK + b) * SPAN;
    #pragma unroll
    for (int u = 0; u < 14; u++) {
        h16x2 o = { (h16)acc[u].x, (h16)acc[u].y };
        *(h16x2*)(dst + 512 * u + 2 * tid) = o;
    }
}

// out[njc][t] = (strip[b1][o1] + strip[b1-1][o1+4096]) / wsq
__global__ __launch_bounds__(256) void k_final(const h16* __restrict__ strips,
        const float2* __restrict__ tw, float* __restrict__ out) {
    int gidx = blockIdx.x * 256 + threadIdx.x;
    int t = gidx * 2;
    if (t >= T_AUDIO) return;
    int njc = blockIdx.y;
    const h16* S = strips + (size_t)njc * NBLK * SPAN;
    float o[2];
    #pragma unroll
    for (int u = 0; u < 2; u++) {
        int tt = t + u;
        int q = tt + PAD;
        int b1 = q >> 12, o1 = q & 4095;
        float s = 0.f;
        if (b1 < NBLK) s += (float)S[b1 * SPAN + o1];
        if (b1 > 0 && o1 < SPAN - 4096) s += (float)S[(b1 - 1) * SPAN + o1 + 4096];
        float wsq;
        if (tt >= 1024 && tt <= 439295) {
            wsq = 1.5f;
        } else {
            wsq = 0.f;
            int ib = q >> 10;
            #pragma unroll
            for (int d = 0; d < 4; d++) {
                int i = ib - d;
                if (i >= 0 && i < NFRAMES) {
                    int m = q - (i << 10);
                    float w = 0.5f - 0.5f * tw[m].x;
                    wsq += w * w;
                }
            }
            if (!(wsq > 1e-11f)) wsq = 1.f;
        }
        o[u] = s / wsq;
    }
    *(float2*)(out + (size_t)njc * T_AUDIO + t) = make_float2(o[0], o[1]);
}

extern "C" void kernel_launch(void* const* d_in, const int* in_sizes, int n_in,
                              void* d_out, int out_size, void* d_ws, size_t ws_size,
                              hipStream_t stream) {
    const float* audio = (const float*)d_in[0];
    const float* Wm    = (const float*)d_in[1];
    const float* bias  = (const float*)d_in[2];
    float* out = (float*)d_out;
    char* ws = (char*)d_ws;

    size_t szWb  = (size_t)4 * GP * KP * sizeof(bf16_t);
    size_t szXb  = (size_t)4 * TPN * KP * sizeof(bf16_t);
    size_t szPh  = (size_t)4 * NFRAMES * KP * sizeof(unsigned);
    size_t szV   = (size_t)16 * NFRAMES * KP * sizeof(bf16_t);
    size_t szStr = (size_t)16 * NBLK * SPAN * sizeof(h16);
    size_t szTw  = (size_t)4096 * sizeof(float2);

    bf16_t*   Wb    = (bf16_t*)ws;   ws += szWb;
    bf16_t*   Xb    = (bf16_t*)ws;   ws += szXb;
    unsigned* ph    = (unsigned*)ws; ws += szPh;
    bf16_t*   V     = (bf16_t*)ws;   ws += szV;
    h16*      strips= (h16*)ws;      ws += szStr;
    float2*   tw    = (float2*)ws;   ws += szTw;
    if ((size_t)(ws - (char*)d_ws) > ws_size) return;

    k_tab<<<dim3(16), 256, 0, stream>>>(tw);
    k_prep<<<dim3(NPREP), 256, 0, stream>>>(audio, Wm, Wb, Xb, ph, tw);
    k_gemm_mfma<<<dim3(72 * 28), 256, 0, stream>>>(Wb, bias, Xb, V);
    k_istft<<<dim3(1728), 256, 0, stream>>>(V, ph, tw, strips);
    k_final<<<dim3((T_AUDIO / 2 + 255) / 256, 16), 256, 0, stream>>>(strips, tw, out);
}

// Round 16
// 206.473 us; speedup vs baseline: 1.1433x; 1.1433x over previous
//
#include <hip/hip_runtime.h>
#include <hip/hip_bf16.h>
#include <math.h>

#define T_AUDIO 441000
#define NH   2048
#define HOP  1024
#define NBINS 2049
#define NFRAMES 431
#define PAD  2048

// GEMM padded dims (bf16 buffers, zero-filled padding -> no guards in GEMM)
#define GP  2176   // padded g (M) = 17*128
#define KP  2112   // padded f (K) = 33*64
#define TPN 448    // padded frames per nc (7*64)

#define NBLK 108   // istft blocks per njc (4 frames each)
#define SPAN 7168  // 4096 + 3*1024 samples per istft block

#define NSTFT (4 * NFRAMES)                      // 1724
#define NCONV ((4 * GP * KP / 8 + 255) / 256)    // 8976
#define NPREP (NSTFT + NCONV + 4)                // +4 Xb pad-row blocks

#define TWO_PI 6.2831853071795864769f

// LDS index padding for FFT buffers: +1 float2 per 16
#define PADI(i) ((i) + ((i) >> 4))

typedef __bf16 bf16_t;
typedef bf16_t bf16x8 __attribute__((ext_vector_type(8)));
typedef bf16_t bf16x4 __attribute__((ext_vector_type(4)));
typedef float f32x4 __attribute__((ext_vector_type(4)));
typedef float f32x4u __attribute__((ext_vector_type(4), aligned(4)));
typedef _Float16 h16;
typedef h16 h16x2 __attribute__((ext_vector_type(2)));

__device__ __forceinline__ unsigned pack_bf2(float a, float b) {
    union { bf16_t h; unsigned short u; } ca, cb;
    ca.h = (bf16_t)a; cb.h = (bf16_t)b;
    return (unsigned)ca.u | ((unsigned)cb.u << 16);
}
__device__ __forceinline__ float2 unpack_bf2(unsigned v) {
    union { unsigned u; float f; } a, b;
    a.u = v << 16;
    b.u = v & 0xffff0000u;
    return make_float2(a.f, b.f);
}

__device__ __forceinline__ float2 cadd(float2 a, float2 b) { return make_float2(a.x + b.x, a.y + b.y); }
__device__ __forceinline__ float2 csub(float2 a, float2 b) { return make_float2(a.x - b.x, a.y - b.y); }
__device__ __forceinline__ float2 cmul(float2 a, float2 b) {       // a*b
    return make_float2(a.x * b.x - a.y * b.y, a.x * b.y + a.y * b.x);
}
__device__ __forceinline__ float2 cmulc(float2 u, float2 w) {      // u*conj(w)
    return make_float2(u.x * w.x + u.y * w.y, u.y * w.x - u.x * w.y);
}

// twiddle table: tw[k] = (cos(2*pi*k/4096), sin(2*pi*k/4096))
__global__ void k_tab(float2* __restrict__ tw) {
    int i = blockIdx.x * 256 + threadIdx.x;
    if (i < 4096) {
        float s, c;
        sincosf((float)i * (TWO_PI / 4096.0f), &s, &c);
        tw[i] = make_float2(c, s);
    }
}

// ---- register-fed Stockham FFT pieces (len 2048, 256 threads) ----

__device__ __forceinline__ void load_own(float2 v[8], const float2* x, int tid) {
    #pragma unroll
    for (int k = 0; k < 8; k++) v[k] = x[PADI(tid + 256 * k)];
}

template<bool FWD>
__device__ __forceinline__ void r8_sweep_store(const float2 v[8], float2* x,
        int tid, int s, int ls, int fac, const float2* __restrict__ tw) {
    const float sgn = FWD ? -1.0f : 1.0f;
    const float R2 = 0.70710678118654752440f;
    int q = tid & (s - 1);
    int p = tid >> ls;
    int e = p * fac;
    float2 w[7];
    #pragma unroll
    for (int k = 0; k < 7; k++) w[k] = tw[e * (k + 1)];
    float2 s0 = cadd(v[0], v[4]), s1 = cadd(v[1], v[5]),
           s2 = cadd(v[2], v[6]), s3 = cadd(v[3], v[7]);
    float2 d0 = csub(v[0], v[4]), d1 = csub(v[1], v[5]),
           d2 = csub(v[2], v[6]), d3 = csub(v[3], v[7]);
    float2 X0, X1, X2, X3, X4, X5, X6, X7;
    {
        float2 t0 = cadd(s0, s2), t1 = csub(s0, s2);
        float2 t2 = cadd(s1, s3), t3 = csub(s1, s3);
        float2 it3 = make_float2(-sgn * t3.y, sgn * t3.x);
        X0 = cadd(t0, t2); X4 = csub(t0, t2);
        X2 = cadd(t1, it3); X6 = csub(t1, it3);
    }
    {
        float2 e0 = d0;
        float2 e1 = make_float2(R2 * (d1.x - sgn * d1.y), R2 * (sgn * d1.x + d1.y));
        float2 e2 = make_float2(-sgn * d2.y, sgn * d2.x);
        float2 e3 = make_float2(-R2 * (d3.x + sgn * d3.y), R2 * (sgn * d3.x - d3.y));
        float2 t0 = cadd(e0, e2), t1 = csub(e0, e2);
        float2 t2 = cadd(e1, e3), t3 = csub(e1, e3);
        float2 it3 = make_float2(-sgn * t3.y, sgn * t3.x);
        X1 = cadd(t0, t2); X5 = csub(t0, t2);
        X3 = cadd(t1, it3); X7 = csub(t1, it3);
    }
    int ob = q + 8 * s * p;
    x[PADI(ob)] = X0;
    float2 XX[7] = {X1, X2, X3, X4, X5, X6, X7};
    #pragma unroll
    for (int k = 0; k < 7; k++) {
        float2 u = XX[k];
        x[PADI(ob + s * (k + 1))] = FWD ? cmulc(u, w[k]) : cmul(w[k], u);
    }
}

__device__ __forceinline__ void r4_final_reg(const float2 v[8], float2 o[8],
                                             float sgn) {
    #pragma unroll
    for (int h = 0; h < 2; h++) {
        float2 c0 = v[h], c1 = v[h + 2], c2 = v[h + 4], c3 = v[h + 6];
        float2 t0 = cadd(c0, c2), t1 = csub(c0, c2);
        float2 t2 = cadd(c1, c3), t3 = csub(c1, c3);
        float2 it3 = make_float2(-sgn * t3.y, sgn * t3.x);
        o[h]     = cadd(t0, t2);
        o[h + 2] = cadd(t1, it3);
        o[h + 4] = csub(t0, t2);
        o[h + 6] = csub(t1, it3);
    }
}

template<bool FWD>
__device__ __forceinline__ void fft_mid(float2 v[8], float2* buf, int tid,
                                        const float2* __restrict__ tw) {
    r8_sweep_store<FWD>(v, buf, tid, 1, 0, 2, tw);
    __syncthreads();
    load_own(v, buf, tid);
    __syncthreads();
    r8_sweep_store<FWD>(v, buf, tid, 8, 3, 16, tw);
    __syncthreads();
    load_own(v, buf, tid);
    __syncthreads();
    r8_sweep_store<FWD>(v, buf, tid, 64, 6, 128, tw);
    __syncthreads();
    load_own(v, buf, tid);
    __syncthreads();
}

// Fused prep: [0,NSTFT) STFT; [NSTFT,NSTFT+NCONV) convW; last 4 = Xb pad rows.
__global__ __launch_bounds__(256) void k_prep(const float* __restrict__ audio,
        const float* __restrict__ W, bf16_t* __restrict__ Wb,
        bf16_t* __restrict__ Xb, unsigned* __restrict__ ph,
        const float2* __restrict__ tw) {
    __shared__ float2 buf[2176];
    int bid = blockIdx.x;
    int tid = threadIdx.x;
    if (bid >= NSTFT) {
        if (bid >= NSTFT + NCONV) {
            // ---- Xb pad rows 431..447 for one nc ----
            int nc = bid - NSTFT - NCONV;
            bf16_t* dst = Xb + ((size_t)nc * TPN + NFRAMES) * KP;
            bf16x8 z = {};
            for (int i = tid; i < (TPN - NFRAMES) * KP / 8; i += 256)
                *(bf16x8*)(dst + (size_t)i * 8) = z;
            return;
        }
        // ---- convW path (vectorized dwordx4 loads) ----
        size_t idx = (size_t)(bid - NSTFT) * 256 + tid;
        size_t total = (size_t)4 * GP * KP / 8;
        if (idx >= total) return;
        size_t e = idx * 8;
        int f0 = (int)(e % KP);
        size_t rem = e / KP;
        int g = (int)(rem % GP);
        int j = (int)(rem / GP);
        bf16x8 v = {};
        if (g < NBINS) {
            const float* src = W + ((size_t)j * NBINS + g) * NBINS;
            if (f0 + 7 < NBINS) {
                f32x4u a0 = *(const f32x4u*)(src + f0);
                f32x4u a1 = *(const f32x4u*)(src + f0 + 4);
                #pragma unroll
                for (int r = 0; r < 4; r++) { v[r] = (bf16_t)a0[r]; v[r + 4] = (bf16_t)a1[r]; }
            } else {
                #pragma unroll
                for (int r = 0; r < 8; r++) {
                    int f = f0 + r;
                    v[r] = (bf16_t)(f < NBINS ? src[f] : 0.0f);
                }
            }
        }
        *(bf16x8*)(Wb + e) = v;
        return;
    }
    // ---- stft path ----
    int nc = bid / NFRAMES;
    int fr = bid - nc * NFRAMES;
    const float* a = audio + (size_t)nc * T_AUDIO;
    int base = fr * HOP - PAD;
    float2 v[8];
    #pragma unroll
    for (int it = 0; it < 8; it++) {
        int m = tid + it * 256;
        float4 tt = ((const float4*)tw)[m];
        float w0 = 0.5f - 0.5f * tt.x, w1 = 0.5f - 0.5f * tt.z;
        int x0 = base + 2 * m;
        if (x0 >= 0 && x0 + 1 < T_AUDIO) {          // fast path: float2 load
            float2 av = *(const float2*)(a + x0);
            v[it] = make_float2(av.x * w0, av.y * w1);
        } else {
            int r0 = x0, r1 = x0 + 1;
            r0 = r0 < 0 ? -r0 : (r0 >= T_AUDIO ? 2 * T_AUDIO - 2 - r0 : r0);
            r1 = r1 < 0 ? -r1 : (r1 >= T_AUDIO ? 2 * T_AUDIO - 2 - r1 : r1);
            v[it] = make_float2(a[r0] * w0, a[r1] * w1);
        }
    }
    fft_mid<true>(v, buf, tid, tw);
    {
        float2 o[8];
        r4_final_reg(v, o, -1.0f);
        #pragma unroll
        for (int it = 0; it < 8; it++) buf[PADI(tid + 256 * it)] = o[it];
    }
    __syncthreads();
    size_t orow = ((size_t)nc * NFRAMES + fr) * KP;
    bf16_t* Xrow = Xb + ((size_t)nc * TPN + fr) * KP;
    for (int k = tid; k < NBINS; k += 256) {
        float2 Zk = buf[PADI(k & 2047)];
        float2 Zm = buf[PADI((2048 - k) & 2047)];
        float ex = 0.5f * (Zk.x + Zm.x), ey = 0.5f * (Zk.y - Zm.y);
        float ox = 0.5f * (Zk.y + Zm.y), oy = -0.5f * (Zk.x - Zm.x);
        float2 w = tw[k];
        float re = ex + w.x * ox + w.y * oy;
        float im = ey + w.x * oy - w.y * ox;
        float mag = sqrtf(re * re + im * im);
        float inv = 1.0f / (mag + 1e-10f);
        Xrow[k] = (bf16_t)mag;
        ph[orow + k] = pack_bf2(re * inv, im * inv);
    }
    // zero the k-tail of this row (replaces global memset of Xb)
    for (int k = NBINS + tid; k < KP; k += 256) Xrow[k] = (bf16_t)0.0f;
}

// V[jnc][t][g] = relu(sum_f W[j][g][f]*X[nc][t][f] + b[j][g]), bf16 out.
// Proven r7 shape: BM=128, BN=64, BK=64; single-buffer, swizzled LDS
// (0 conflicts); XCD-grouped 1D grid (72 groups x 28 = 2016, 1904 real).
__global__ __launch_bounds__(256) void k_gemm_mfma(const bf16_t* __restrict__ Wb,
        const float* __restrict__ bias, const bf16_t* __restrict__ Xb,
        bf16_t* __restrict__ V) {
    __shared__ bf16_t As[128 * 64];   // 16 KB
    __shared__ bf16_t Bs[64 * 64];    // 8 KB
    int id = blockIdx.x;
    int xcd = id & 7, nn = id >> 3;
    int G = xcd + 8 * (nn / 28);      // group = (j,g0); G%8 == xcd
    if (G >= 68) return;              // 72-group padding
    int m28 = nn % 28;
    int j  = G / 17;
    int g0 = (G % 17) * 128;
    int nc = m28 / 7;
    int t0 = (m28 % 7) * 64;
    const bf16_t* A = Wb + ((size_t)j * GP + g0) * KP;
    const bf16_t* B = Xb + ((size_t)nc * TPN + t0) * KP;
    int tid = threadIdx.x;
    int lane = tid & 63, wid = tid >> 6;
    int wm = wid >> 1, wn = wid & 1;

    const bf16_t* srcA[4];
    #pragma unroll
    for (int i = 0; i < 4; i++) {
        int s = i * 256 + tid;
        int r = s >> 3, cc = (s & 7) ^ (r & 7);
        srcA[i] = A + (size_t)r * KP + cc * 8;
    }
    const bf16_t* srcB[2];
    #pragma unroll
    for (int i = 0; i < 2; i++) {
        int s = i * 256 + tid;
        int r = s >> 3, cc = (s & 7) ^ (r & 7);
        srcB[i] = B + (size_t)r * KP + cc * 8;
    }

    int laneLo = lane & 15, laneHi = lane >> 4;
    int offA[4][2], offB[2][2];
    #pragma unroll
    for (int mm = 0; mm < 4; mm++) {
        int r = wm * 64 + mm * 16 + laneLo;
        #pragma unroll
        for (int kk = 0; kk < 2; kk++) {
            int c = kk * 4 + laneHi;
            offA[mm][kk] = r * 128 + ((c ^ (r & 7)) << 4);
        }
    }
    #pragma unroll
    for (int n = 0; n < 2; n++) {
        int r = wn * 32 + n * 16 + laneLo;
        #pragma unroll
        for (int kk = 0; kk < 2; kk++) {
            int c = kk * 4 + laneHi;
            offB[n][kk] = r * 128 + ((c ^ (r & 7)) << 4);
        }
    }

    f32x4 acc[4][2];
    #pragma unroll
    for (int mm = 0; mm < 4; mm++)
        #pragma unroll
        for (int n = 0; n < 2; n++)
            acc[mm][n] = (f32x4){0.f, 0.f, 0.f, 0.f};

    for (int k0 = 0; k0 < KP; k0 += 64) {
        #pragma unroll
        for (int i = 0; i < 4; i++)
            __builtin_amdgcn_global_load_lds(
                (const __attribute__((address_space(1))) void*)(srcA[i] + k0),
                (__attribute__((address_space(3))) void*)(As + (i * 256 + tid) * 8),
                16, 0, 0);
        #pragma unroll
        for (int i = 0; i < 2; i++)
            __builtin_amdgcn_global_load_lds(
                (const __attribute__((address_space(1))) void*)(srcB[i] + k0),
                (__attribute__((address_space(3))) void*)(Bs + (i * 256 + tid) * 8),
                16, 0, 0);
        __syncthreads();

        bf16x8 af[4][2], bfr[2][2];
        #pragma unroll
        for (int mm = 0; mm < 4; mm++)
            #pragma unroll
            for (int kk = 0; kk < 2; kk++)
                af[mm][kk] = *(const bf16x8*)((const char*)As + offA[mm][kk]);
        #pragma unroll
        for (int n = 0; n < 2; n++)
            #pragma unroll
            for (int kk = 0; kk < 2; kk++)
                bfr[n][kk] = *(const bf16x8*)((const char*)Bs + offB[n][kk]);
        #pragma unroll
        for (int mm = 0; mm < 4; mm++)
            #pragma unroll
            for (int n = 0; n < 2; n++)
                #pragma unroll
                for (int kk = 0; kk < 2; kk++)
                    acc[mm][n] = __builtin_amdgcn_mfma_f32_16x16x32_bf16(
                        af[mm][kk], bfr[n][kk], acc[mm][n], 0, 0, 0);
        __syncthreads();
    }

    int jnc = j * 4 + nc;
    int colT = laneLo;
    int rowB = laneHi * 4;
    #pragma unroll
    for (int n = 0; n < 2; n++) {
        int t = t0 + wn * 32 + n * 16 + colT;
        if (t >= NFRAMES) continue;
        size_t vrow = ((size_t)jnc * NFRAMES + t) * KP;
        #pragma unroll
        for (int mm = 0; mm < 4; mm++) {
            int g = g0 + wm * 64 + mm * 16 + rowB;
            if (g + 3 < NBINS) {
                bf16x4 o;
                #pragma unroll
                for (int r = 0; r < 4; r++)
                    o[r] = (bf16_t)fmaxf(acc[mm][n][r] + bias[j * NBINS + g + r], 0.0f);
                *(bf16x4*)(V + vrow + g) = o;
            } else {
                #pragma unroll
                for (int r = 0; r < 4; r++) {
                    int gg = g + r;
                    if (gg < NBINS)
                        V[vrow + gg] = (bf16_t)fmaxf(acc[mm][n][r] + bias[j * NBINS + gg], 0.0f);
                }
            }
        }
    }
}

// One block per (jnc, 4 frames). Per frame: stage V row (4KB) + ph row (8KB)
// into LDS via coalesced global_load_lds (issued one frame AHEAD, latency
// hides under the FFT); z-build reads LDS; final radix-4 + window + OLA in
// registers. XCD/j-grouped 1D grid (1728 = 8 x 216).
__global__ __launch_bounds__(256) void k_istft(const bf16_t* __restrict__ V,
        const unsigned* __restrict__ ph, const float2* __restrict__ tw,
        h16* __restrict__ strips) {
    __shared__ float2 buf[2176];
    __shared__ __align__(16) unsigned char stg[12336];
    bf16_t*   Vs = (bf16_t*)stg;              // 2056 bf16 (4112 B)
    unsigned* Ps = (unsigned*)(stg + 4112);   // 2052 u32  (8208 B)
    int id = blockIdx.x;                 // 1728 = 8 XCD x 216
    int xcd = id & 7, slot = id >> 3;
    int wgid = xcd * 216 + slot;         // bijective
    int j = wgid & 3;
    int t4 = wgid >> 2;                  // nc*108 + b
    int nc = t4 / NBLK;
    int b  = t4 - nc * NBLK;
    int njc = (nc >> 1) * 8 + j * 2 + (nc & 1);
    int jnc = j * 4 + nc;
    int tid = threadIdx.x;
    const float scale = 1.0f / 2048.0f;
    float2 acc[14];
    #pragma unroll
    for (int u = 0; u < 14; u++) acc[u] = make_float2(0.f, 0.f);

#define STAGE_F(fr_)                                                           \
    {                                                                          \
        const bf16_t* vsrc = V + ((size_t)jnc * NFRAMES + (fr_)) * KP;         \
        const unsigned* psrc = ph + ((size_t)nc * NFRAMES + (fr_)) * KP;       \
        __builtin_amdgcn_global_load_lds(                                      \
            (const __attribute__((address_space(1))) void*)(vsrc + tid * 8),   \
            (__attribute__((address_space(3))) void*)(Vs + tid * 8), 16, 0, 0);\
        __builtin_amdgcn_global_load_lds(                                      \
            (const __attribute__((address_space(1))) void*)(psrc + tid * 4),   \
            (__attribute__((address_space(3))) void*)(Ps + tid * 4), 16, 0, 0);\
        __builtin_amdgcn_global_load_lds(                                      \
            (const __attribute__((address_space(1))) void*)(psrc + 1024 + tid * 4), \
            (__attribute__((address_space(3))) void*)(Ps + 1024 + tid * 4), 16, 0, 0); \
        if (tid == 0) {                                                        \
            __builtin_amdgcn_global_load_lds(                                  \
                (const __attribute__((address_space(1))) void*)(vsrc + 2048),  \
                (__attribute__((address_space(3))) void*)(Vs + 2048), 16, 0, 0); \
            __builtin_amdgcn_global_load_lds(                                  \
                (const __attribute__((address_space(1))) void*)(psrc + 2048),  \
                (__attribute__((address_space(3))) void*)(Ps + 2048), 16, 0, 0); \
        }                                                                      \
    }

    STAGE_F(b * 4);
    __syncthreads();   // vmcnt(0) drain + barrier: stage ready

    #pragma unroll
    for (int p = 0; p < 4; p++) {
        int fr = b * 4 + p;
        if (fr < NFRAMES) {   // block-uniform guard
            float2 v[8];
            // z-build from staged LDS (2-way/conflict-free reads)
            #pragma unroll
            for (int it = 0; it < 8; it++) {
                int k = tid + it * 256;
                int km = 2048 - k;
                float vk = (float)Vs[k];
                float2 pk = unpack_bf2(Ps[k]);
                float vm = (float)Vs[km];
                float2 pm = unpack_bf2(Ps[km]);
                float2 Yk = make_float2(vk * pk.x, vk * pk.y);
                float2 Ym = make_float2(vm * pm.x, vm * pm.y);
                float ex = 0.5f * (Yk.x + Ym.x), ey = 0.5f * (Yk.y - Ym.y);
                float wx = 0.5f * (Yk.x - Ym.x), wy = 0.5f * (Yk.y + Ym.y);
                float2 w = tw[k];
                float ox_ = w.x * wx - w.y * wy;
                float oy_ = w.x * wy + w.y * wx;
                v[it] = make_float2(ex - oy_, ey + ox_);
            }
            __syncthreads();            // all waves done reading the stage
            if (p < 3) STAGE_F(fr + 1); // prefetch next frame (lands by the
                                        // fft's first barrier; overlaps sweep0)
            fft_mid<false>(v, buf, tid, tw);
            float2 o[8];
            r4_final_reg(v, o, 1.0f);
            #pragma unroll
            for (int it = 0; it < 8; it++) {
                int m = tid + it * 256;
                float4 tt = ((const float4*)tw)[m];
                acc[2 * p + it].x += o[it].x * scale * (0.5f - 0.5f * tt.x);
                acc[2 * p + it].y += o[it].y * scale * (0.5f - 0.5f * tt.z);
            }
        }
    }
#undef STAGE_F
    h16* dst = strips + ((size_t)njc * NBLK + b) * SPAN;
    #pragma unroll
    for (int u = 0; u < 14; u++) {
        h16x2 o = { (h16)acc[u].x, (h16)acc[u].y };
        *(h16x2*)(dst + 512 * u + 2 * tid) = o;
    }
}

// out[njc][t] = (strip[b1][o1] + strip[b1-1][o1+4096]) / wsq
__global__ __launch_bounds__(256) void k_final(const h16* __restrict__ strips,
        const float2* __restrict__ tw, float* __restrict__ out) {
    int gidx = blockIdx.x * 256 + threadIdx.x;
    int t = gidx * 2;
    if (t >= T_AUDIO) return;
    int njc = blockIdx.y;
    const h16* S = strips + (size_t)njc * NBLK * SPAN;
    float o[2];
    #pragma unroll
    for (int u = 0; u < 2; u++) {
        int tt = t + u;
        int q = tt + PAD;
        int b1 = q >> 12, o1 = q & 4095;
        float s = 0.f;
        if (b1 < NBLK) s += (float)S[b1 * SPAN + o1];
        if (b1 > 0 && o1 < SPAN - 4096) s += (float)S[(b1 - 1) * SPAN + o1 + 4096];
        float wsq;
        if (tt >= 1024 && tt <= 439295) {
            wsq = 1.5f;
        } else {
            wsq = 0.f;
            int ib = q >> 10;
            #pragma unroll
            for (int d = 0; d < 4; d++) {
                int i = ib - d;
                if (i >= 0 && i < NFRAMES) {
                    int m = q - (i << 10);
                    float w = 0.5f - 0.5f * tw[m].x;
                    wsq += w * w;
                }
            }
            if (!(wsq > 1e-11f)) wsq = 1.f;
        }
        o[u] = s / wsq;
    }
    *(float2*)(out + (size_t)njc * T_AUDIO + t) = make_float2(o[0], o[1]);
}

extern "C" void kernel_launch(void* const* d_in, const int* in_sizes, int n_in,
                              void* d_out, int out_size, void* d_ws, size_t ws_size,
                              hipStream_t stream) {
    const float* audio = (const float*)d_in[0];
    const float* Wm    = (const float*)d_in[1];
    const float* bias  = (const float*)d_in[2];
    float* out = (float*)d_out;
    char* ws = (char*)d_ws;

    size_t szWb  = (size_t)4 * GP * KP * sizeof(bf16_t);
    size_t szXb  = (size_t)4 * TPN * KP * sizeof(bf16_t);
    size_t szPh  = (size_t)4 * NFRAMES * KP * sizeof(unsigned);
    size_t szV   = (size_t)16 * NFRAMES * KP * sizeof(bf16_t);
    size_t szStr = (size_t)16 * NBLK * SPAN * sizeof(h16);
    size_t szTw  = (size_t)4096 * sizeof(float2);

    bf16_t*   Wb    = (bf16_t*)ws;   ws += szWb;
    bf16_t*   Xb    = (bf16_t*)ws;   ws += szXb;
    unsigned* ph    = (unsigned*)ws; ws += szPh;
    bf16_t*   V     = (bf16_t*)ws;   ws += szV;
    h16*      strips= (h16*)ws;      ws += szStr;
    float2*   tw    = (float2*)ws;   ws += szTw;
    if ((size_t)(ws - (char*)d_ws) > ws_size) return;

    k_tab<<<dim3(16), 256, 0, stream>>>(tw);
    k_prep<<<dim3(NPREP), 256, 0, stream>>>(audio, Wm, Wb, Xb, ph, tw);
    k_gemm_mfma<<<dim3(72 * 28), 256, 0, stream>>>(Wb, bias, Xb, V);
    k_istft<<<dim3(1728), 256, 0, stream>>>(V, ph, tw, strips);
    k_final<<<dim3((T_AUDIO / 2 + 255) / 256, 16), 256, 0, stream>>>(strips, tw, out);
}